// Round 14
// baseline (3353.784 us; speedup 1.0000x reference)
//
#include <hip/hip_runtime.h>
#include <math.h>

#define NS   512   // states
#define NO   1024  // observations
#define NB   64    // batch
#define TMAX 512

#define QLDS 8     // uint4 chunks (8 fp16 k-values) in LDS: k 0..63
#define QSTR 56    // uint4 chunks streamed from XCD L2 every step: k 64..511

typedef _Float16 h2v __attribute__((ext_vector_type(2)));

__device__ inline float wave_red_sum(float x) {
#pragma unroll
  for (int o = 32; o; o >>= 1) x += __shfl_xor(x, o, 64);
  return x;
}
__device__ inline float wave_red_max(float x) {
#pragma unroll
  for (int o = 32; o; o >>= 1) x = fmaxf(x, __shfl_xor(x, o, 64));
  return x;
}

__device__ inline float dot2u(unsigned int a, unsigned int b, float c) {
#if __has_builtin(__builtin_amdgcn_fdot2)
  return __builtin_amdgcn_fdot2(__builtin_bit_cast(h2v, a),
                                __builtin_bit_cast(h2v, b), c, false);
#else
  h2v av = __builtin_bit_cast(h2v, a), bv = __builtin_bit_cast(h2v, b);
  return c + (float)av.x * (float)bv.x + (float)av.y * (float)bv.y;
#endif
}

// P1: pi softmax -> pi_sm[512]
__global__ void k_pi(const float* __restrict__ pi, float* __restrict__ pi_sm) {
  __shared__ float red[8];
  int tid = threadIdx.x;
  float v = pi[tid];
  float m = wave_red_max(v);
  if ((tid & 63) == 0) red[tid >> 6] = m;
  __syncthreads();
  m = fmaxf(fmaxf(fmaxf(red[0], red[1]), fmaxf(red[2], red[3])),
            fmaxf(fmaxf(red[4], red[5]), fmaxf(red[6], red[7])));
  float e = __expf(v - m);
  float s = wave_red_sum(e);
  __syncthreads();
  if ((tid & 63) == 0) red[tid >> 6] = s;
  __syncthreads();
  s = red[0] + red[1] + red[2] + red[3] + red[4] + red[5] + red[6] + red[7];
  pi_sm[tid] = e / s;
}

// P2: column logsumexp of A (axis 0). One block (256 thr) per column. grid 512.
__global__ void k_colLse(const float* __restrict__ A, float* __restrict__ lseA) {
  __shared__ float redm[4];
  __shared__ float reds[4];
  int k = blockIdx.x, tid = threadIdx.x;
  float a0 = A[tid * NS + k], a1 = A[(tid + 256) * NS + k];
  float m = wave_red_max(fmaxf(a0, a1));
  if ((tid & 63) == 0) redm[tid >> 6] = m;
  __syncthreads();
  m = fmaxf(fmaxf(redm[0], redm[1]), fmaxf(redm[2], redm[3]));
  float s = __expf(a0 - m) + __expf(a1 - m);
  s = wave_red_sum(s);
  if ((tid & 63) == 0) reds[tid >> 6] = s;
  __syncthreads();
  s = reds[0] + reds[1] + reds[2] + reds[3];
  if (tid == 0) lseA[k] = m + __logf(s);
}

// P3: row logsumexp of E (axis 1). One block per row. grid 512 x 256.
__global__ void k_rowLseE(const float* __restrict__ E, float* __restrict__ lseE) {
  __shared__ float red[4];
  int i = blockIdx.x, tid = threadIdx.x;
  const float* row = E + i * NO;
  float a0 = row[tid], a1 = row[tid + 256], a2 = row[tid + 512], a3 = row[tid + 768];
  float m = fmaxf(fmaxf(a0, a1), fmaxf(a2, a3));
  m = wave_red_max(m);
  if ((tid & 63) == 0) red[tid >> 6] = m;
  __syncthreads();
  m = fmaxf(fmaxf(red[0], red[1]), fmaxf(red[2], red[3]));
  float s = __expf(a0 - m) + __expf(a1 - m) + __expf(a2 - m) + __expf(a3 - m);
  s = wave_red_sum(s);
  __syncthreads();
  if ((tid & 63) == 0) red[tid >> 6] = s;
  __syncthreads();
  s = red[0] + red[1] + red[2] + red[3];
  if (tid == 0) lseE[i] = m + __logf(s);
}

// P4: pack A_exp = exp(A - lseA[col]) fp16, chunk-major:
// uint4 chunk Aall[q*512 + i] = row i, k = 8q..8q+7. Word
// W[(q*512+i)*4 + h] packs k = 8q+2h, 8q+2h+1. grid 256 x 512.
__global__ void k_pack(const float* __restrict__ A, const float* __restrict__ lseA,
                       unsigned int* __restrict__ W) {
  int u = blockIdx.x * 512 + threadIdx.x;   // [0, 64*512*4)
  int q = u >> 11;
  int r = u & 2047;
  int i = r >> 2;
  int h = r & 3;
  int k0 = q * 8 + h * 2;
  float e0 = __expf(A[i * NS + k0]     - lseA[k0]);
  float e1 = __expf(A[i * NS + k0 + 1] - lseA[k0 + 1]);
  h2v p;
  p.x = (_Float16)e0;
  p.y = (_Float16)e1;
  W[u] = __builtin_bit_cast(unsigned int, p);
}

// Main forward: one block (512 thr, 8 waves) per batch; thread tid = state i.
// Pipe-balanced A split (r11 audit): LDS-private b128 reads cost ~96 cy/chunk/CU
// (12 cy/wave x 8 waves) vs ~36 cy/chunk for an XCD-L2 stream (224 B/cy/CU
// share; all 8 blocks/XCD read the SAME L2 copy of packed A -- FETCH flat in
// all successful rounds). r1/r11 had the ratio backwards (19 LDS / 45 stream).
// Optimum ~8 LDS / 56 streamed. No pinning: the compiler schedules the
// in-loop stream well (r1/r11 measured), forcing residency always lost
// (r3/r5/r7/r10).
// Deferred pow2 rescale, ONE barrier/step (r11: -100us, absmax 0.0).
// [resubmit #3: r12/r13 were broker-level container failures, not source]
__global__ __launch_bounds__(512, 1) void k_fwd(
    const float* __restrict__ E, const int* __restrict__ x,
    const int* __restrict__ Tlen, const float* __restrict__ pi_sm,
    const float* __restrict__ lseE, const uint4* __restrict__ Aall,
    float* __restrict__ out) {
  __shared__ uint4 Alds[QLDS * 512];            // 64 KB
  __shared__ uint4 vbuf[2][NS / 8];             // 2 KB ping-pong (fp16 u)
  __shared__ int xrow[TMAX];                    // 2 KB
  __shared__ __align__(16) float red[2][8];     // ping-pong sigma partials
  int b = blockIdx.x, tid = threadIdx.x;

  // Prologue: LDS chunks k 0..63; xrow.
#pragma unroll
  for (int q = 0; q < QLDS; q++) Alds[q * 512 + tid] = Aall[q * 512 + tid];
  for (int t = tid; t < TMAX; t += 512) xrow[t] = x[b * TMAX + t];

  float pi_i  = pi_sm[tid];
  float lse_i = lseE[tid];
  const float* Erow = E + tid * NO;
  int Tb = Tlen[b];
  float c = 0.f;        // log2-domain accumulator
  float Dlog = 0.f;     // log2 d_{t-1}
  int gexp_prev = 19;
  int cur = 0;
  __syncthreads();

  for (int t = 0; t < Tb; t++) {
    int nxt = cur ^ 1;
    float epre = Erow[xrow[t]];     // issued early; latency hides under dot
    int gexpw;
    if (t == 0) {
      gexpw = 19;
    } else {
      // consume previous step's sigma (deferred; gates only the u-write)
      const float4* rp = (const float4*)red[cur];
      float4 ra = rp[0], rb = rp[1];
      float sp = ((ra.x + ra.y) + (ra.z + ra.w)) + ((rb.x + rb.y) + (rb.z + rb.w));
      float ls = __log2f(sp);
      int e = ((__builtin_bit_cast(int, sp) >> 23) & 0xff) - 126;  // sp = m*2^e
      c += ls - Dlog;                 // += log2 s_{t-1}
      Dlog = (float)gexp_prev + ls;   // log2 d_{t-1}
      gexpw = 19 - gexp_prev - e;
    }
    float acc;
    if (t == 0) {
      acc = pi_i;
    } else {
      float a0 = 0.f, a1 = 0.f, a2 = 0.f, a3 = 0.f;
      const uint4* vp = vbuf[cur];
#pragma unroll
      for (int q = 0; q < QLDS; q++) {          // LDS chunks k 0..63
        uint4 av = Alds[q * 512 + tid];
        uint4 vv = vp[q];
        a0 = dot2u(av.x, vv.x, a0);
        a1 = dot2u(av.y, vv.y, a1);
        a2 = dot2u(av.z, vv.z, a2);
        a3 = dot2u(av.w, vv.w, a3);
      }
#pragma unroll
      for (int q = 0; q < QSTR; q++) {          // streamed chunks k 64..511
        uint4 av = Aall[(QLDS + q) * 512 + tid];
        uint4 vv = vp[QLDS + q];
        a0 = dot2u(av.x, vv.x, a0);
        a1 = dot2u(av.y, vv.y, a1);
        a2 = dot2u(av.z, vv.z, a2);
        a3 = dot2u(av.w, vv.w, a3);
      }
      acc = (a0 + a1) + (a2 + a3);
    }
    float em = __expf(epre - lse_i);
    float raw = acc * em;
    // write scaled u (exact pow2 scale); avg component mid-fp16-range
    ((_Float16*)vbuf[nxt])[tid] = (_Float16)ldexpf(raw, gexpw);
    // reduce raw for next step's sigma
    float s = wave_red_sum(raw);
    if ((tid & 63) == 0) red[nxt][tid >> 6] = s;
    gexp_prev = gexpw;
    cur = nxt;
    __syncthreads();
  }
  // final: consume last step's sigma
  {
    const float4* rp = (const float4*)red[cur];
    float4 ra = rp[0], rb = rp[1];
    float sp = ((ra.x + ra.y) + (ra.z + ra.w)) + ((rb.x + rb.y) + (rb.z + rb.w));
    c += __log2f(sp) - Dlog;
  }
  if (tid == 0) out[b] = c * 0.69314718055994530942f;
}

extern "C" void kernel_launch(void* const* d_in, const int* in_sizes, int n_in,
                              void* d_out, int out_size, void* d_ws, size_t ws_size,
                              hipStream_t stream) {
  const float* pi = (const float*)d_in[0];
  const float* A  = (const float*)d_in[1];
  const float* E  = (const float*)d_in[2];
  const int*   x  = (const int*)d_in[3];
  const int*   T  = (const int*)d_in[4];
  float* out = (float*)d_out;

  char* ws = (char*)d_ws;
  float*        pi_sm = (float*)(ws + 0);
  float*        lseA  = (float*)(ws + 2048);
  float*        lseE  = (float*)(ws + 4096);
  unsigned int* Apk   = (unsigned int*)(ws + 6144);  // 512*512 fp16 = 512 KB

  hipLaunchKernelGGL(k_pi,      dim3(1),   dim3(512), 0, stream, pi, pi_sm);
  hipLaunchKernelGGL(k_colLse,  dim3(512), dim3(256), 0, stream, A, lseA);
  hipLaunchKernelGGL(k_rowLseE, dim3(512), dim3(256), 0, stream, E, lseE);
  hipLaunchKernelGGL(k_pack,    dim3(256), dim3(512), 0, stream, A, lseA, Apk);
  hipLaunchKernelGGL(k_fwd,     dim3(64),  dim3(512), 0, stream,
                     E, x, T, pi_sm, lseE, (const uint4*)Apk, out);
}

// Round 15
// 1262.691 us; speedup vs baseline: 2.6561x; 2.6561x over previous
//
#include <hip/hip_runtime.h>
#include <math.h>

#define NS   512   // states
#define NO   1024  // observations
#define NB   64    // batch
#define TMAX 512

// A stored as fp8 e5m2, scaled x256. 32 uint4 chunks of 16 k-values each.
#define QREG 22    // chunks 0..21: areg[] -- compiler keeps ~half in VGPRs,
                   // software-pipelines the rest from L2 (r11-proven regime)
#define QLDS 10    // chunks 22..31 in LDS (80 KB)

typedef _Float16 h2v __attribute__((ext_vector_type(2)));

__device__ inline float wave_red_sum(float x) {
#pragma unroll
  for (int o = 32; o; o >>= 1) x += __shfl_xor(x, o, 64);
  return x;
}
__device__ inline float wave_red_max(float x) {
#pragma unroll
  for (int o = 32; o; o >>= 1) x = fmaxf(x, __shfl_xor(x, o, 64));
  return x;
}

__device__ inline float dot2u(unsigned int a, unsigned int b, float c) {
#if __has_builtin(__builtin_amdgcn_fdot2)
  return __builtin_amdgcn_fdot2(__builtin_bit_cast(h2v, a),
                                __builtin_bit_cast(h2v, b), c, false);
#else
  h2v av = __builtin_bit_cast(h2v, a), bv = __builtin_bit_cast(h2v, b);
  return c + (float)av.x * (float)bv.x + (float)av.y * (float)bv.y;
#endif
}

// e5m2 -> fp16 expansion: exact byte shift (same exponent width).
// lo: bytes 0,1 -> fp16 pair {b0<<8, b1<<8}; hi: bytes 2,3.
__device__ inline unsigned int ex_lo(unsigned int w) {
#if __has_builtin(__builtin_amdgcn_perm)
  return __builtin_amdgcn_perm(0u, w, 0x010C000Cu);
#else
  return ((w & 0xFFu) << 8) | ((w & 0xFF00u) << 16);
#endif
}
__device__ inline unsigned int ex_hi(unsigned int w) {
#if __has_builtin(__builtin_amdgcn_perm)
  return __builtin_amdgcn_perm(0u, w, 0x030C020Cu);
#else
  return ((w & 0x00FF0000u) >> 8) | (w & 0xFF000000u);
#endif
}

// float -> e5m2 byte (RTNE via fp16 then round mantissa 10->2 bits).
__device__ inline unsigned int f2e5m2(float f) {
  unsigned short hb = __builtin_bit_cast(unsigned short, (_Float16)f);
  unsigned int r = (unsigned int)hb + 0x7Fu + ((hb >> 8) & 1u);
  return (r >> 8) & 0xFFu;
}

// P1: pi softmax -> pi_sm[512]
__global__ void k_pi(const float* __restrict__ pi, float* __restrict__ pi_sm) {
  __shared__ float red[8];
  int tid = threadIdx.x;
  float v = pi[tid];
  float m = wave_red_max(v);
  if ((tid & 63) == 0) red[tid >> 6] = m;
  __syncthreads();
  m = fmaxf(fmaxf(fmaxf(red[0], red[1]), fmaxf(red[2], red[3])),
            fmaxf(fmaxf(red[4], red[5]), fmaxf(red[6], red[7])));
  float e = __expf(v - m);
  float s = wave_red_sum(e);
  __syncthreads();
  if ((tid & 63) == 0) red[tid >> 6] = s;
  __syncthreads();
  s = red[0] + red[1] + red[2] + red[3] + red[4] + red[5] + red[6] + red[7];
  pi_sm[tid] = e / s;
}

// P2: column logsumexp of A (axis 0). One block (256 thr) per column. grid 512.
__global__ void k_colLse(const float* __restrict__ A, float* __restrict__ lseA) {
  __shared__ float redm[4];
  __shared__ float reds[4];
  int k = blockIdx.x, tid = threadIdx.x;
  float a0 = A[tid * NS + k], a1 = A[(tid + 256) * NS + k];
  float m = wave_red_max(fmaxf(a0, a1));
  if ((tid & 63) == 0) redm[tid >> 6] = m;
  __syncthreads();
  m = fmaxf(fmaxf(redm[0], redm[1]), fmaxf(redm[2], redm[3]));
  float s = __expf(a0 - m) + __expf(a1 - m);
  s = wave_red_sum(s);
  if ((tid & 63) == 0) reds[tid >> 6] = s;
  __syncthreads();
  s = reds[0] + reds[1] + reds[2] + reds[3];
  if (tid == 0) lseA[k] = m + __logf(s);
}

// P3: row logsumexp of E (axis 1). One block per row. grid 512 x 256.
__global__ void k_rowLseE(const float* __restrict__ E, float* __restrict__ lseE) {
  __shared__ float red[4];
  int i = blockIdx.x, tid = threadIdx.x;
  const float* row = E + i * NO;
  float a0 = row[tid], a1 = row[tid + 256], a2 = row[tid + 512], a3 = row[tid + 768];
  float m = fmaxf(fmaxf(a0, a1), fmaxf(a2, a3));
  m = wave_red_max(m);
  if ((tid & 63) == 0) red[tid >> 6] = m;
  __syncthreads();
  m = fmaxf(fmaxf(red[0], red[1]), fmaxf(red[2], red[3]));
  float s = __expf(a0 - m) + __expf(a1 - m) + __expf(a2 - m) + __expf(a3 - m);
  s = wave_red_sum(s);
  __syncthreads();
  if ((tid & 63) == 0) red[tid >> 6] = s;
  __syncthreads();
  s = red[0] + red[1] + red[2] + red[3];
  if (tid == 0) lseE[i] = m + __logf(s);
}

// P4: pack A_exp8 = e5m2(exp(A - lseA[col]) * 256), chunk-major:
// uint4 chunk Apk[q*512 + i] = row i, k = 16q..16q+15.
// u32 word W[(q*512+i)*4 + h] = bytes k = 16q+4h+{0,1,2,3}. grid 128 x 512.
__global__ void k_pack(const float* __restrict__ A, const float* __restrict__ lseA,
                       unsigned int* __restrict__ W) {
  int u = blockIdx.x * 512 + threadIdx.x;   // [0, 65536)
  int h = u & 3;
  int qi = u >> 2;
  int i = qi & 511;
  int q = qi >> 9;
  int k0 = q * 16 + h * 4;
  const float* row = A + i * NS;
  unsigned int b0 = f2e5m2(__expf(row[k0]     - lseA[k0])     * 256.f);
  unsigned int b1 = f2e5m2(__expf(row[k0 + 1] - lseA[k0 + 1]) * 256.f);
  unsigned int b2 = f2e5m2(__expf(row[k0 + 2] - lseA[k0 + 2]) * 256.f);
  unsigned int b3 = f2e5m2(__expf(row[k0 + 3] - lseA[k0 + 3]) * 256.f);
  W[u] = b0 | (b1 << 8) | (b2 << 16) | (b3 << 24);
}

// Main forward: one block (512 thr, 8 waves) per batch; thread tid = state i.
// r11 structure (857us, best) with A in fp8 e5m2 (x256 scale, exact pow2):
// halves every A-byte on every pipe (LDS private reads 19->10 chunks,
// register/stream tier 45->22 chunks, L2 copy 512->256 KB). e5m2->fp16 is
// an exact byte shift: 1 v_perm per fp16-pair feeding fdot2. r14's lesson
// baked in: keep the areg[] register tier (compiler software-pipelines it);
// never push the A-stream wholesale to L2 (29 B/cy/CU achieved, not 224).
// Deferred pow2 rescale, ONE barrier/step (r11-proven, absmax 0.0).
__global__ __launch_bounds__(512, 1) void k_fwd(
    const float* __restrict__ E, const int* __restrict__ x,
    const int* __restrict__ Tlen, const float* __restrict__ pi_sm,
    const float* __restrict__ lseE, const uint4* __restrict__ Aall,
    float* __restrict__ out) {
  __shared__ uint4 Alds[QLDS * 512];            // 80 KB
  __shared__ uint4 vbuf[2][NS / 8];             // 2 KB ping-pong (fp16 u)
  __shared__ int xrow[TMAX];                    // 2 KB
  __shared__ __align__(16) float red[2][8];     // ping-pong sigma partials
  int b = blockIdx.x, tid = threadIdx.x;

  // A chunks: 22 "register" chunks (compiler keeps/streams) + 10 LDS chunks.
  uint4 areg[QREG];
#pragma unroll
  for (int q = 0; q < QREG; q++) areg[q] = Aall[q * 512 + tid];
#pragma unroll
  for (int q = 0; q < QLDS; q++) Alds[q * 512 + tid] = Aall[(QREG + q) * 512 + tid];

  for (int t = tid; t < TMAX; t += 512) xrow[t] = x[b * TMAX + t];

  float pi_i  = pi_sm[tid];
  float lse_i = lseE[tid];
  const float* Erow = E + tid * NO;
  int Tb = Tlen[b];
  float c = 0.f;        // log2-domain accumulator
  float Dlog = 0.f;     // log2 d_{t-1}
  int gexp_prev = 19;
  int cur = 0;
  __syncthreads();

  for (int t = 0; t < Tb; t++) {
    int nxt = cur ^ 1;
    float epre = Erow[xrow[t]];     // issued early; latency hides under dot
    int gexpw;
    if (t == 0) {
      gexpw = 19;
    } else {
      // consume previous step's sigma (deferred; gates only the u-write)
      const float4* rp = (const float4*)red[cur];
      float4 ra = rp[0], rb = rp[1];
      float sp = ((ra.x + ra.y) + (ra.z + ra.w)) + ((rb.x + rb.y) + (rb.z + rb.w));
      float ls = __log2f(sp);
      int e = ((__builtin_bit_cast(int, sp) >> 23) & 0xff) - 126;  // sp = m*2^e
      c += ls - Dlog;                 // += log2 s_{t-1}
      Dlog = (float)gexp_prev + ls;   // log2 d_{t-1}
      gexpw = 19 - gexp_prev - e;
    }
    float acc;
    if (t == 0) {
      acc = pi_i;
    } else {
      float a0 = 0.f, a1 = 0.f, a2 = 0.f, a3 = 0.f;
      const uint4* vp = vbuf[cur];
#pragma unroll
      for (int q = 0; q < QREG; q++) {          // register-tier chunks
        uint4 av = areg[q];
        uint4 va = vp[2 * q];                   // u pairs k=16q..16q+7
        uint4 vb = vp[2 * q + 1];               // u pairs k=16q+8..16q+15
        a0 = dot2u(ex_lo(av.x), va.x, a0);
        a0 = dot2u(ex_hi(av.x), va.y, a0);
        a1 = dot2u(ex_lo(av.y), va.z, a1);
        a1 = dot2u(ex_hi(av.y), va.w, a1);
        a2 = dot2u(ex_lo(av.z), vb.x, a2);
        a2 = dot2u(ex_hi(av.z), vb.y, a2);
        a3 = dot2u(ex_lo(av.w), vb.z, a3);
        a3 = dot2u(ex_hi(av.w), vb.w, a3);
      }
#pragma unroll
      for (int q = 0; q < QLDS; q++) {          // LDS chunks
        uint4 av = Alds[q * 512 + tid];
        int cq = QREG + q;
        uint4 va = vp[2 * cq];
        uint4 vb = vp[2 * cq + 1];
        a0 = dot2u(ex_lo(av.x), va.x, a0);
        a0 = dot2u(ex_hi(av.x), va.y, a0);
        a1 = dot2u(ex_lo(av.y), va.z, a1);
        a1 = dot2u(ex_hi(av.y), va.w, a1);
        a2 = dot2u(ex_lo(av.z), vb.x, a2);
        a2 = dot2u(ex_hi(av.z), vb.y, a2);
        a3 = dot2u(ex_lo(av.w), vb.z, a3);
        a3 = dot2u(ex_hi(av.w), vb.w, a3);
      }
      acc = ((a0 + a1) + (a2 + a3)) * 0.00390625f;   // undo x256 A-scale
    }
    float em = __expf(epre - lse_i);
    float raw = acc * em;
    // write scaled u (exact pow2 scale)
    ((_Float16*)vbuf[nxt])[tid] = (_Float16)ldexpf(raw, gexpw);
    // reduce raw for next step's sigma
    float s = wave_red_sum(raw);
    if ((tid & 63) == 0) red[nxt][tid >> 6] = s;
    gexp_prev = gexpw;
    cur = nxt;
    __syncthreads();
  }
  // final: consume last step's sigma
  {
    const float4* rp = (const float4*)red[cur];
    float4 ra = rp[0], rb = rp[1];
    float sp = ((ra.x + ra.y) + (ra.z + ra.w)) + ((rb.x + rb.y) + (rb.z + rb.w));
    c += __log2f(sp) - Dlog;
  }
  if (tid == 0) out[b] = c * 0.69314718055994530942f;
}

extern "C" void kernel_launch(void* const* d_in, const int* in_sizes, int n_in,
                              void* d_out, int out_size, void* d_ws, size_t ws_size,
                              hipStream_t stream) {
  const float* pi = (const float*)d_in[0];
  const float* A  = (const float*)d_in[1];
  const float* E  = (const float*)d_in[2];
  const int*   x  = (const int*)d_in[3];
  const int*   T  = (const int*)d_in[4];
  float* out = (float*)d_out;

  char* ws = (char*)d_ws;
  float*        pi_sm = (float*)(ws + 0);
  float*        lseA  = (float*)(ws + 2048);
  float*        lseE  = (float*)(ws + 4096);
  unsigned int* Apk   = (unsigned int*)(ws + 6144);  // 512*512 fp8 = 256 KB

  hipLaunchKernelGGL(k_pi,      dim3(1),   dim3(512), 0, stream, pi, pi_sm);
  hipLaunchKernelGGL(k_colLse,  dim3(512), dim3(256), 0, stream, A, lseA);
  hipLaunchKernelGGL(k_rowLseE, dim3(512), dim3(256), 0, stream, E, lseE);
  hipLaunchKernelGGL(k_pack,    dim3(128), dim3(512), 0, stream, A, lseA, Apk);
  hipLaunchKernelGGL(k_fwd,     dim3(64),  dim3(512), 0, stream,
                     E, x, T, pi_sm, lseE, (const uint4*)Apk, out);
}

// Round 16
// 886.461 us; speedup vs baseline: 3.7833x; 1.4244x over previous
//
#include <hip/hip_runtime.h>
#include <math.h>

#define NS   512   // states
#define NO   1024  // observations
#define NB   64    // batch
#define TMAX 512

// Per-thread A: 64 uint4 chunks (8 fp16 k-values each), chunk c = j*8+m:
// output 64j+l, k-slice [64w+8m, +8). c 0..47 -> areg (compiler keeps ~18,
// software-pipelines the rest from L2 -- r11-proven regime); c 48..63 -> LDS.
#define QREG 48
#define QLDS 16

typedef _Float16 h2v __attribute__((ext_vector_type(2)));

__device__ inline float wave_red_sum(float x) {
#pragma unroll
  for (int o = 32; o; o >>= 1) x += __shfl_xor(x, o, 64);
  return x;
}
__device__ inline float wave_red_max(float x) {
#pragma unroll
  for (int o = 32; o; o >>= 1) x = fmaxf(x, __shfl_xor(x, o, 64));
  return x;
}

__device__ inline float dot2u(unsigned int a, unsigned int b, float c) {
#if __has_builtin(__builtin_amdgcn_fdot2)
  return __builtin_amdgcn_fdot2(__builtin_bit_cast(h2v, a),
                                __builtin_bit_cast(h2v, b), c, false);
#else
  h2v av = __builtin_bit_cast(h2v, a), bv = __builtin_bit_cast(h2v, b);
  return c + (float)av.x * (float)bv.x + (float)av.y * (float)bv.y;
#endif
}

// P1: pi softmax -> pi_sm[512]
__global__ void k_pi(const float* __restrict__ pi, float* __restrict__ pi_sm) {
  __shared__ float red[8];
  int tid = threadIdx.x;
  float v = pi[tid];
  float m = wave_red_max(v);
  if ((tid & 63) == 0) red[tid >> 6] = m;
  __syncthreads();
  m = fmaxf(fmaxf(fmaxf(red[0], red[1]), fmaxf(red[2], red[3])),
            fmaxf(fmaxf(red[4], red[5]), fmaxf(red[6], red[7])));
  float e = __expf(v - m);
  float s = wave_red_sum(e);
  __syncthreads();
  if ((tid & 63) == 0) red[tid >> 6] = s;
  __syncthreads();
  s = red[0] + red[1] + red[2] + red[3] + red[4] + red[5] + red[6] + red[7];
  pi_sm[tid] = e / s;
}

// P2: column logsumexp of A (axis 0). One block (256 thr) per column. grid 512.
__global__ void k_colLse(const float* __restrict__ A, float* __restrict__ lseA) {
  __shared__ float redm[4];
  __shared__ float reds[4];
  int k = blockIdx.x, tid = threadIdx.x;
  float a0 = A[tid * NS + k], a1 = A[(tid + 256) * NS + k];
  float m = wave_red_max(fmaxf(a0, a1));
  if ((tid & 63) == 0) redm[tid >> 6] = m;
  __syncthreads();
  m = fmaxf(fmaxf(redm[0], redm[1]), fmaxf(redm[2], redm[3]));
  float s = __expf(a0 - m) + __expf(a1 - m);
  s = wave_red_sum(s);
  if ((tid & 63) == 0) reds[tid >> 6] = s;
  __syncthreads();
  s = reds[0] + reds[1] + reds[2] + reds[3];
  if (tid == 0) lseA[k] = m + __logf(s);
}

// P3: row logsumexp of E (axis 1). One block per row. grid 512 x 256.
__global__ void k_rowLseE(const float* __restrict__ E, float* __restrict__ lseE) {
  __shared__ float red[4];
  int i = blockIdx.x, tid = threadIdx.x;
  const float* row = E + i * NO;
  float a0 = row[tid], a1 = row[tid + 256], a2 = row[tid + 512], a3 = row[tid + 768];
  float m = fmaxf(fmaxf(a0, a1), fmaxf(a2, a3));
  m = wave_red_max(m);
  if ((tid & 63) == 0) red[tid >> 6] = m;
  __syncthreads();
  m = fmaxf(fmaxf(red[0], red[1]), fmaxf(red[2], red[3]));
  float s = __expf(a0 - m) + __expf(a1 - m) + __expf(a2 - m) + __expf(a3 - m);
  s = wave_red_sum(s);
  __syncthreads();
  if ((tid & 63) == 0) red[tid >> 6] = s;
  __syncthreads();
  s = red[0] + red[1] + red[2] + red[3];
  if (tid == 0) lseE[i] = m + __logf(s);
}

// P4: pack A_exp = exp(A - lseA[col]) fp16 for the k-split layout.
// k_fwd thread t (w=t>>6, l=t&63) handles outputs i=64j+l (j=0..7) on
// k-slice [64w, 64w+64). Chunk c=j*8+m: uint4 Apk[c*512+t] = output 64j+l,
// k = 64w+8m..+7. Word u = (c*512+t)*4 + h packs k = 64w+8m+2h, +1.
// grid 256 x 512.
__global__ void k_pack(const float* __restrict__ A, const float* __restrict__ lseA,
                       unsigned int* __restrict__ W) {
  int u = blockIdx.x * 512 + threadIdx.x;   // [0, 131072)
  int h = u & 3;
  int ct = u >> 2;
  int t = ct & 511;
  int c = ct >> 9;
  int j = c >> 3, m = c & 7;
  int w = t >> 6, l = t & 63;
  int i  = 64 * j + l;
  int k0 = 64 * w + 8 * m + 2 * h;
  float e0 = __expf(A[i * NS + k0]     - lseA[k0]);
  float e1 = __expf(A[i * NS + k0 + 1] - lseA[k0 + 1]);
  h2v p;
  p.x = (_Float16)e0;
  p.y = (_Float16)e1;
  W[u] = __builtin_bit_cast(unsigned int, p);
}

// Main forward: one block (512 thr, 8 waves) per batch; 8-way k-split.
// Wave w owns k-slice [64w, 64w+64): reads only ITS 8 uniform u-chunks
// (uniform-read storm 512 -> 64 insts/CU/step -- the r11 critical-path
// audit's biggest term). Lane l computes partials for outputs {64j+l},
// exchanged via Pf[8][512] (lane-consecutive, conflict-free).
// Three-tier A per thread unchanged from r11 (areg 48 / LDS 16 / stream).
// Deferred pow2 rescale (r11-proven, absmax 0.0). fp8 reverted (r15: VALU
// doubled, -350us).
__global__ __launch_bounds__(512, 1) void k_fwd(
    const float* __restrict__ E, const int* __restrict__ x,
    const int* __restrict__ Tlen, const float* __restrict__ pi_sm,
    const float* __restrict__ lseE, const uint4* __restrict__ Apk,
    float* __restrict__ out) {
  __shared__ uint4 Alds[QLDS * 512];            // 128 KB
  __shared__ float Pf[8 * 512];                 // 16 KB partials P[kk][i]
  __shared__ uint4 vbuf[2][NS / 8];             // 2 KB ping-pong (fp16 u)
  __shared__ int xrow[TMAX];                    // 2 KB
  __shared__ __align__(16) float red[2][8];     // ping-pong sigma partials
  int b = blockIdx.x, tid = threadIdx.x;
  int w = tid >> 6, l = tid & 63;

  // Prologue: chunks 0..47 -> areg (compiler tiers), 48..63 -> LDS.
  uint4 areg[QREG];
#pragma unroll
  for (int q = 0; q < QREG; q++) areg[q] = Apk[q * 512 + tid];
#pragma unroll
  for (int q = 0; q < QLDS; q++) Alds[q * 512 + tid] = Apk[(QREG + q) * 512 + tid];

  for (int t2 = tid; t2 < TMAX; t2 += 512) xrow[t2] = x[b * TMAX + t2];

  float pi_i  = pi_sm[tid];
  float lse_i = lseE[tid];
  const float* Erow = E + tid * NO;
  int Tb = Tlen[b];
  float c = 0.f;        // log2-domain accumulator
  float Dlog = 0.f;     // log2 d_{t-1}
  int gexp_prev = 19;
  int cur = 0;
  __syncthreads();

  for (int t = 0; t < Tb; t++) {
    int nxt = cur ^ 1;
    float epre = Erow[xrow[t]];     // issued early; latency hides under dot
    int gexpw;
    if (t == 0) {
      gexpw = 19;
    } else {
      // consume previous step's sigma (deferred; gates only the u-write)
      const float4* rp = (const float4*)red[cur];
      float4 ra = rp[0], rb = rp[1];
      float sp = ((ra.x + ra.y) + (ra.z + ra.w)) + ((rb.x + rb.y) + (rb.z + rb.w));
      float ls = __log2f(sp);
      int e = ((__builtin_bit_cast(int, sp) >> 23) & 0xff) - 126;  // sp = m*2^e
      c += ls - Dlog;                 // += log2 s_{t-1}
      Dlog = (float)gexp_prev + ls;   // log2 d_{t-1}
      gexpw = 19 - gexp_prev - e;
    }
    if (t) {
      const uint4* vp = vbuf[cur];
      // wave's 8 uniform u-chunks (k-slice [64w, 64w+64))
      uint4 uv0 = vp[8 * w + 0], uv1 = vp[8 * w + 1];
      uint4 uv2 = vp[8 * w + 2], uv3 = vp[8 * w + 3];
      uint4 uv4 = vp[8 * w + 4], uv5 = vp[8 * w + 5];
      uint4 uv6 = vp[8 * w + 6], uv7 = vp[8 * w + 7];
      float acc[8];
#pragma unroll
      for (int j = 0; j < 8; j++) acc[j] = 0.f;
#pragma unroll
      for (int j = 0; j < 8; j++) {
#pragma unroll
        for (int m = 0; m < 8; m++) {
          int cq = j * 8 + m;   // compile-time constant (full unroll)
          uint4 av = (cq < QREG) ? areg[cq] : Alds[(cq - QREG) * 512 + tid];
          uint4 uv = (m == 0) ? uv0 : (m == 1) ? uv1 : (m == 2) ? uv2 :
                     (m == 3) ? uv3 : (m == 4) ? uv4 : (m == 5) ? uv5 :
                     (m == 6) ? uv6 : uv7;
          acc[j] = dot2u(av.x, uv.x, acc[j]);
          acc[j] = dot2u(av.y, uv.y, acc[j]);
          acc[j] = dot2u(av.z, uv.z, acc[j]);
          acc[j] = dot2u(av.w, uv.w, acc[j]);
        }
      }
      // partials: P[w][64j + l] -- lanes consecutive, conflict-free
#pragma unroll
      for (int j = 0; j < 8; j++) Pf[w * 512 + j * 64 + l] = acc[j];
    }
    __syncthreads();   // bar1: partials visible

    // Owner phase: thread tid owns state i = tid.
    {
      float em = __expf(epre - lse_i);
      float raw;
      if (t) {
        float s0 = Pf[tid]          + Pf[512 + tid];
        float s1 = Pf[1024 + tid]   + Pf[1536 + tid];
        float s2 = Pf[2048 + tid]   + Pf[2560 + tid];
        float s3 = Pf[3072 + tid]   + Pf[3584 + tid];
        raw = ((s0 + s1) + (s2 + s3)) * em;
      } else {
        raw = pi_i * em;
      }
      // write scaled u (exact pow2 scale)
      ((_Float16*)vbuf[nxt])[tid] = (_Float16)ldexpf(raw, gexpw);
      // reduce raw for next step's sigma
      float s = wave_red_sum(raw);
      if (l == 0) red[nxt][w] = s;
      gexp_prev = gexpw;
    }
    __syncthreads();   // bar2: u + sigma visible
    cur = nxt;
  }
  // final: consume last step's sigma
  {
    const float4* rp = (const float4*)red[cur];
    float4 ra = rp[0], rb = rp[1];
    float sp = ((ra.x + ra.y) + (ra.z + ra.w)) + ((rb.x + rb.y) + (rb.z + rb.w));
    c += __log2f(sp) - Dlog;
  }
  if (tid == 0) out[b] = c * 0.69314718055994530942f;
}

extern "C" void kernel_launch(void* const* d_in, const int* in_sizes, int n_in,
                              void* d_out, int out_size, void* d_ws, size_t ws_size,
                              hipStream_t stream) {
  const float* pi = (const float*)d_in[0];
  const float* A  = (const float*)d_in[1];
  const float* E  = (const float*)d_in[2];
  const int*   x  = (const int*)d_in[3];
  const int*   T  = (const int*)d_in[4];
  float* out = (float*)d_out;

  char* ws = (char*)d_ws;
  float*        pi_sm = (float*)(ws + 0);
  float*        lseA  = (float*)(ws + 2048);
  float*        lseE  = (float*)(ws + 4096);
  unsigned int* Apk   = (unsigned int*)(ws + 6144);  // 512*512 fp16 = 512 KB

  hipLaunchKernelGGL(k_pi,      dim3(1),   dim3(512), 0, stream, pi, pi_sm);
  hipLaunchKernelGGL(k_colLse,  dim3(512), dim3(256), 0, stream, A, lseA);
  hipLaunchKernelGGL(k_rowLseE, dim3(512), dim3(256), 0, stream, E, lseE);
  hipLaunchKernelGGL(k_pack,    dim3(256), dim3(512), 0, stream, A, lseA, Apk);
  hipLaunchKernelGGL(k_fwd,     dim3(64),  dim3(512), 0, stream,
                     E, x, T, pi_sm, lseE, (const uint4*)Apk, out);
}

// Round 17
// 833.279 us; speedup vs baseline: 4.0248x; 1.0638x over previous
//
#include <hip/hip_runtime.h>
#include <math.h>

#define NS   512   // states
#define NO   1024  // observations
#define NB   64    // batch
#define TMAX 512

// Per-thread A: 64 uint4 chunks (8 fp16 k-values each), chunk c = j*8+m:
// output 64j+l, k = 64w+8m..+7. c 0..49 -> areg (compiler keeps ~20,
// software-pipelines the rest from L2 -- r11/r16-proven regime);
// c 50..63 -> LDS (14 chunks, 112 KB; capacity bound by Pf ping-pong).
#define QREG 50
#define QLDS 14

typedef _Float16 h2v __attribute__((ext_vector_type(2)));

__device__ inline float wave_red_sum(float x) {
#pragma unroll
  for (int o = 32; o; o >>= 1) x += __shfl_xor(x, o, 64);
  return x;
}
__device__ inline float wave_red_max(float x) {
#pragma unroll
  for (int o = 32; o; o >>= 1) x = fmaxf(x, __shfl_xor(x, o, 64));
  return x;
}

__device__ inline float dot2u(unsigned int a, unsigned int b, float c) {
#if __has_builtin(__builtin_amdgcn_fdot2)
  return __builtin_amdgcn_fdot2(__builtin_bit_cast(h2v, a),
                                __builtin_bit_cast(h2v, b), c, false);
#else
  h2v av = __builtin_bit_cast(h2v, a), bv = __builtin_bit_cast(h2v, b);
  return c + (float)av.x * (float)bv.x + (float)av.y * (float)bv.y;
#endif
}

// P1: pi softmax -> pi_sm[512]
__global__ void k_pi(const float* __restrict__ pi, float* __restrict__ pi_sm) {
  __shared__ float red[8];
  int tid = threadIdx.x;
  float v = pi[tid];
  float m = wave_red_max(v);
  if ((tid & 63) == 0) red[tid >> 6] = m;
  __syncthreads();
  m = fmaxf(fmaxf(fmaxf(red[0], red[1]), fmaxf(red[2], red[3])),
            fmaxf(fmaxf(red[4], red[5]), fmaxf(red[6], red[7])));
  float e = __expf(v - m);
  float s = wave_red_sum(e);
  __syncthreads();
  if ((tid & 63) == 0) red[tid >> 6] = s;
  __syncthreads();
  s = red[0] + red[1] + red[2] + red[3] + red[4] + red[5] + red[6] + red[7];
  pi_sm[tid] = e / s;
}

// P2: column logsumexp of A (axis 0). One block (256 thr) per column. grid 512.
__global__ void k_colLse(const float* __restrict__ A, float* __restrict__ lseA) {
  __shared__ float redm[4];
  __shared__ float reds[4];
  int k = blockIdx.x, tid = threadIdx.x;
  float a0 = A[tid * NS + k], a1 = A[(tid + 256) * NS + k];
  float m = wave_red_max(fmaxf(a0, a1));
  if ((tid & 63) == 0) redm[tid >> 6] = m;
  __syncthreads();
  m = fmaxf(fmaxf(redm[0], redm[1]), fmaxf(redm[2], redm[3]));
  float s = __expf(a0 - m) + __expf(a1 - m);
  s = wave_red_sum(s);
  if ((tid & 63) == 0) reds[tid >> 6] = s;
  __syncthreads();
  s = reds[0] + reds[1] + reds[2] + reds[3];
  if (tid == 0) lseA[k] = m + __logf(s);
}

// P3: row logsumexp of E (axis 1). One block per row. grid 512 x 256.
__global__ void k_rowLseE(const float* __restrict__ E, float* __restrict__ lseE) {
  __shared__ float red[4];
  int i = blockIdx.x, tid = threadIdx.x;
  const float* row = E + i * NO;
  float a0 = row[tid], a1 = row[tid + 256], a2 = row[tid + 512], a3 = row[tid + 768];
  float m = fmaxf(fmaxf(a0, a1), fmaxf(a2, a3));
  m = wave_red_max(m);
  if ((tid & 63) == 0) red[tid >> 6] = m;
  __syncthreads();
  m = fmaxf(fmaxf(red[0], red[1]), fmaxf(red[2], red[3]));
  float s = __expf(a0 - m) + __expf(a1 - m) + __expf(a2 - m) + __expf(a3 - m);
  s = wave_red_sum(s);
  __syncthreads();
  if ((tid & 63) == 0) red[tid >> 6] = s;
  __syncthreads();
  s = red[0] + red[1] + red[2] + red[3];
  if (tid == 0) lseE[i] = m + __logf(s);
}

// P4: pack A_exp = exp(A - lseA[col]) fp16 for the k-split layout.
// k_fwd thread t (w=t>>6, l=t&63) handles outputs i=64j+l (j=0..7) on
// k-slice [64w, 64w+64). Chunk c=j*8+m: uint4 Apk[c*512+t] = output 64j+l,
// k = 64w+8m..+7. Word u = (c*512+t)*4 + h packs k = 64w+8m+2h, +1.
// grid 256 x 512.
__global__ void k_pack(const float* __restrict__ A, const float* __restrict__ lseA,
                       unsigned int* __restrict__ W) {
  int u = blockIdx.x * 512 + threadIdx.x;   // [0, 131072)
  int h = u & 3;
  int ct = u >> 2;
  int t = ct & 511;
  int c = ct >> 9;
  int j = c >> 3, m = c & 7;
  int w = t >> 6, l = t & 63;
  int i  = 64 * j + l;
  int k0 = 64 * w + 8 * m + 2 * h;
  float e0 = __expf(A[i * NS + k0]     - lseA[k0]);
  float e1 = __expf(A[i * NS + k0 + 1] - lseA[k0 + 1]);
  h2v p;
  p.x = (_Float16)e0;
  p.y = (_Float16)e1;
  W[u] = __builtin_bit_cast(unsigned int, p);
}

// Main forward: one block (512 thr, 8 waves) per batch; 8-way k-split with
// ONE barrier per step. Key invariant: wave w's u-slice k in [64w, 64w+64)
// is produced by wave w's OWN lanes (i = tid = 64w+l) -- same-wave LDS ops
// are in-order, so the u round-trip needs NO barrier and a SINGLE buffer.
// The one barrier protects Pf (ping-pong kills the WAR) and red[] (deferred
// sigma: write at owner(t), read at owner(t+1), exactly one barrier apart).
// Three-tier A per thread (areg 50 / LDS 14 / compiler stream) -- r16-proven.
// Deferred pow2 rescale (r11-proven, absmax 0.0).
__global__ __launch_bounds__(512, 1) void k_fwd(
    const float* __restrict__ E, const int* __restrict__ x,
    const int* __restrict__ Tlen, const float* __restrict__ pi_sm,
    const float* __restrict__ lseE, const uint4* __restrict__ Apk,
    float* __restrict__ out) {
  __shared__ uint4 Alds[QLDS * 512];            // 112 KB
  __shared__ float Pf[2][8 * 512];              // 32 KB ping-pong partials
  __shared__ uint4 ubuf[NS / 8];                // 1 KB u (fp16), single buffer
  __shared__ int xrow[TMAX];                    // 2 KB
  __shared__ __align__(16) float red[2][8];     // ping-pong sigma partials
  int b = blockIdx.x, tid = threadIdx.x;
  int w = tid >> 6, l = tid & 63;

  // Prologue: chunks 0..49 -> areg (compiler tiers), 50..63 -> LDS.
  uint4 areg[QREG];
#pragma unroll
  for (int q = 0; q < QREG; q++) areg[q] = Apk[q * 512 + tid];
#pragma unroll
  for (int q = 0; q < QLDS; q++) Alds[q * 512 + tid] = Apk[(QREG + q) * 512 + tid];

  for (int t2 = tid; t2 < TMAX; t2 += 512) xrow[t2] = x[b * TMAX + t2];

  float pi_i  = pi_sm[tid];
  float lse_i = lseE[tid];
  const float* Erow = E + tid * NO;
  int Tb = Tlen[b];
  float c = 0.f;        // log2-domain accumulator
  float Dlog = 0.f;     // log2 d_{t-1}
  int gexp_prev = 19;
  int cur = 0;          // parity for Pf and red
  __syncthreads();

  for (int t = 0; t < Tb; t++) {
    int nxt = cur ^ 1;
    float epre = Erow[xrow[t]];     // issued early; latency hides under dot
    if (t) {
      // dot: wave reads its OWN 8 uniform u-chunks (written by this wave's
      // lanes at owner(t-1); same-wave DS ops are in-order -> no barrier)
      uint4 uv0 = ubuf[8 * w + 0], uv1 = ubuf[8 * w + 1];
      uint4 uv2 = ubuf[8 * w + 2], uv3 = ubuf[8 * w + 3];
      uint4 uv4 = ubuf[8 * w + 4], uv5 = ubuf[8 * w + 5];
      uint4 uv6 = ubuf[8 * w + 6], uv7 = ubuf[8 * w + 7];
      float acc[8];
#pragma unroll
      for (int j = 0; j < 8; j++) acc[j] = 0.f;
#pragma unroll
      for (int j = 0; j < 8; j++) {
#pragma unroll
        for (int m = 0; m < 8; m++) {
          int cq = j * 8 + m;   // compile-time constant (full unroll)
          uint4 av = (cq < QREG) ? areg[cq] : Alds[(cq - QREG) * 512 + tid];
          uint4 uv = (m == 0) ? uv0 : (m == 1) ? uv1 : (m == 2) ? uv2 :
                     (m == 3) ? uv3 : (m == 4) ? uv4 : (m == 5) ? uv5 :
                     (m == 6) ? uv6 : uv7;
          acc[j] = dot2u(av.x, uv.x, acc[j]);
          acc[j] = dot2u(av.y, uv.y, acc[j]);
          acc[j] = dot2u(av.z, uv.z, acc[j]);
          acc[j] = dot2u(av.w, uv.w, acc[j]);
        }
      }
      // partials: Pf[cur][w][64j + l] -- lanes consecutive, conflict-free
#pragma unroll
      for (int j = 0; j < 8; j++) Pf[cur][w * 512 + j * 64 + l] = acc[j];
    }
    __syncthreads();   // THE barrier: Pf(cur) + red(cur) visible

    // Owner phase: thread tid owns state i = tid (= 64w + l, own wave).
    {
      int gexpw = 19;
      if (t) {
        // consume sigma of step t-1 (written at owner(t-1), 1 barrier ago)
        const float4* rp = (const float4*)red[cur];
        float4 ra = rp[0], rb = rp[1];
        float sp = ((ra.x + ra.y) + (ra.z + ra.w)) + ((rb.x + rb.y) + (rb.z + rb.w));
        float ls = __log2f(sp);
        int e = ((__builtin_bit_cast(int, sp) >> 23) & 0xff) - 126;  // sp=m*2^e
        c += ls - Dlog;
        Dlog = (float)gexp_prev + ls;
        gexpw = 19 - gexp_prev - e;
      }
      float em = __expf(epre - lse_i);
      float raw;
      if (t) {
        const float* pf = Pf[cur];
        float s0 = pf[tid]          + pf[512 + tid];
        float s1 = pf[1024 + tid]   + pf[1536 + tid];
        float s2 = pf[2048 + tid]   + pf[2560 + tid];
        float s3 = pf[3072 + tid]   + pf[3584 + tid];
        raw = ((s0 + s1) + (s2 + s3)) * em;
      } else {
        raw = pi_i * em;
      }
      // u[tid]: consumed only by this wave's dot(t+1) -- no barrier needed
      ((_Float16*)ubuf)[tid] = (_Float16)ldexpf(raw, gexpw);
      // sigma partial for step t, consumed at owner(t+1) after next barrier
      float s = wave_red_sum(raw);
      if (l == 0) red[nxt][w] = s;
      gexp_prev = gexpw;
    }
    cur = nxt;
  }
  // final: consume last step's sigma (written at owner(Tb-1) to red[cur])
  __syncthreads();
  {
    const float4* rp = (const float4*)red[cur];
    float4 ra = rp[0], rb = rp[1];
    float sp = ((ra.x + ra.y) + (ra.z + ra.w)) + ((rb.x + rb.y) + (rb.z + rb.w));
    c += __log2f(sp) - Dlog;
  }
  if (tid == 0) out[b] = c * 0.69314718055994530942f;
}

extern "C" void kernel_launch(void* const* d_in, const int* in_sizes, int n_in,
                              void* d_out, int out_size, void* d_ws, size_t ws_size,
                              hipStream_t stream) {
  const float* pi = (const float*)d_in[0];
  const float* A  = (const float*)d_in[1];
  const float* E  = (const float*)d_in[2];
  const int*   x  = (const int*)d_in[3];
  const int*   T  = (const int*)d_in[4];
  float* out = (float*)d_out;

  char* ws = (char*)d_ws;
  float*        pi_sm = (float*)(ws + 0);
  float*        lseA  = (float*)(ws + 2048);
  float*        lseE  = (float*)(ws + 4096);
  unsigned int* Apk   = (unsigned int*)(ws + 6144);  // 512*512 fp16 = 512 KB

  hipLaunchKernelGGL(k_pi,      dim3(1),   dim3(512), 0, stream, pi, pi_sm);
  hipLaunchKernelGGL(k_colLse,  dim3(512), dim3(256), 0, stream, A, lseA);
  hipLaunchKernelGGL(k_rowLseE, dim3(512), dim3(256), 0, stream, E, lseE);
  hipLaunchKernelGGL(k_pack,    dim3(256), dim3(512), 0, stream, A, lseA, Apk);
  hipLaunchKernelGGL(k_fwd,     dim3(64),  dim3(512), 0, stream,
                     E, x, T, pi_sm, lseE, (const uint4*)Apk, out);
}